// Round 17
// baseline (248.409 us; speedup 1.0000x reference)
//
#include <hip/hip_runtime.h>

typedef __attribute__((ext_vector_type(8))) short short8;
typedef __attribute__((ext_vector_type(4))) float f32x4;
typedef __attribute__((ext_vector_type(4))) unsigned short ushort4v;

struct DB0 { static constexpr int value = 0; };
struct DB1 { static constexpr int value = 1; };
struct DB2 { static constexpr int value = 2; };

__device__ __forceinline__ unsigned short f2bf(float f) {
  unsigned int u = __float_as_uint(f);
  u += 0x7fffu + ((u >> 16) & 1u);
  return (unsigned short)(u >> 16);
}
__device__ __forceinline__ float bf2f(unsigned short h) {
  return __uint_as_float(((unsigned int)h) << 16);
}

__device__ __forceinline__ void gload16(const unsigned short* g, unsigned short* l) {
  __builtin_amdgcn_global_load_lds(
      (const __attribute__((address_space(1))) unsigned int*)g,
      (__attribute__((address_space(3))) unsigned int*)l,
      16, 0, 0);
}

template <int OFF>
__device__ __forceinline__ short8 dsr(unsigned a) {
  short8 r;
  asm volatile("ds_read_b128 %0, %1 offset:%2" : "=v"(r) : "v"(a), "n"(OFF));
  return r;
}

__device__ __forceinline__ void bar() {
  asm volatile("" ::: "memory");
  __builtin_amdgcn_s_barrier();
  asm volatile("" ::: "memory");
}

// ---- merged prep: conv x->bf16 (8192 blks) | W_attn^T (3072) | W_proj^T (1024)
__global__ __launch_bounds__(256) void prep_kernel(
    const float* __restrict__ x, unsigned short* __restrict__ xb,
    const float* __restrict__ Wa, unsigned short* __restrict__ wta,
    const float* __restrict__ Wp, unsigned short* __restrict__ wtp) {
  int b = blockIdx.x;
  int tx = threadIdx.x & 31, ty = threadIdx.x >> 5;
  if (b < 8192) {
    int i = b * 256 + threadIdx.x;
    f32x4 v = ((const f32x4*)x)[i];
    ushort4v o;
    o[0] = f2bf(v[0]); o[1] = f2bf(v[1]); o[2] = f2bf(v[2]); o[3] = f2bf(v[3]);
    ((ushort4v*)xb)[i] = o;
    return;
  }
  const float* W; unsigned short* Wt; int K, N, n0, k0;
  if (b < 8192 + 3072) {
    int bb = b - 8192; W = Wa; Wt = wta; K = 1024; N = 3072;
    n0 = (bb % 96) * 32; k0 = (bb / 96) * 32;
  } else {
    int bb = b - 11264; W = Wp; Wt = wtp; K = 1024; N = 1024;
    n0 = (bb % 32) * 32; k0 = (bb / 32) * 32;
  }
  __shared__ float tile[32][33];
#pragma unroll
  for (int j = 0; j < 32; j += 8)
    tile[ty + j][tx] = W[(size_t)(k0 + ty + j) * N + n0 + tx];
  __syncthreads();
#pragma unroll
  for (int j = 0; j < 32; j += 8)
    Wt[(size_t)(n0 + ty + j) * K + k0 + tx] = f2bf(tile[tx][ty + j]);
}

// ======== r6 GEMM body: 128x128, BK=64, depth-2, drain schedule ========
template <int OUTBF>
__device__ __forceinline__ void gemm_body(
    unsigned short (*lds)[16384],
    const unsigned short* __restrict__ A, int lda,
    const unsigned short* __restrict__ Bt, int ldb,
    void* __restrict__ Cv, int ldc,
    const float* __restrict__ bias, int NT, float scale, bool maskC,
    int m0, int n0) {
  const int t = threadIdx.x;
  const int lane = t & 63, wid = t >> 6;
  const int g = lane >> 4, q = lane & 15;
  const int wm = wid >> 1, wn = wid & 1;

  f32x4 acc[4][4] = {};

  {
    const int scol = ((t & 7) * 8) ^ ((t & 32) >> 1);
    const unsigned short* aS = A + (size_t)(m0 + (t >> 3)) * lda + scol;
    const unsigned short* bS = Bt + (size_t)(n0 + (t >> 3)) * ldb + scol;

    auto stage = [&](int tt) {
      unsigned short* d = &lds[tt & 1][wid * 512];
      const unsigned short* sa = aS + (size_t)tt * 64;
      const unsigned short* sb = bS + (size_t)tt * 64;
      gload16(sa, d);
      gload16(sa + (size_t)32 * lda, d + 2048);
      gload16(sa + (size_t)64 * lda, d + 4096);
      gload16(sa + (size_t)96 * lda, d + 6144);
      gload16(sb, d + 8192);
      gload16(sb + (size_t)32 * ldb, d + 10240);
      gload16(sb + (size_t)64 * ldb, d + 12288);
      gload16(sb + (size_t)96 * ldb, d + 14336);
    };

    const unsigned base =
        (unsigned)(unsigned long long)(__attribute__((address_space(3))) unsigned short*)&lds[0][0];
    const int colA = (g * 16) ^ ((q & 4) << 3);
    const unsigned aaB = base + (unsigned)((wm * 64 + q) * 128 + colA);
    const unsigned bbB = base + 16384u + (unsigned)((wn * 64 + q) * 128 + colA);

    stage(0);
    asm volatile("s_waitcnt vmcnt(0)" ::: "memory");
    bar();

    auto body = [&](auto dbc, int tt) {
      constexpr int DB = decltype(dbc)::value;
      const unsigned aa = aaB + DB * 32768u;
      const unsigned bb = bbB + DB * 32768u;
      if (tt + 1 < NT) stage(tt + 1);
      short8 aq[4][2], bq[4][2];
#pragma unroll
      for (int m = 0; m < 4; m++) {
        aq[m][0] = dsr<0>(aa + m * 2048u);
        aq[m][1] = dsr<64>(aa + m * 2048u);
      }
#pragma unroll
      for (int n = 0; n < 4; n++) {
        bq[n][0] = dsr<0>(bb + n * 2048u);
        bq[n][1] = dsr<64>(bb + n * 2048u);
      }
      asm volatile("s_waitcnt lgkmcnt(0)" ::: "memory");
      __builtin_amdgcn_sched_barrier(0);
      __builtin_amdgcn_s_setprio(1);
#pragma unroll
      for (int ks = 0; ks < 2; ks++)
#pragma unroll
        for (int m = 0; m < 4; m++)
#pragma unroll
          for (int n = 0; n < 4; n++)
            acc[m][n] = __builtin_amdgcn_mfma_f32_16x16x32_bf16(aq[m][ks], bq[n][ks], acc[m][n], 0, 0, 0);
      __builtin_amdgcn_s_setprio(0);
      __builtin_amdgcn_sched_barrier(0);
      asm volatile("s_waitcnt vmcnt(0)" ::: "memory");
      bar();
    };

    int tt = 0;
    for (; tt + 2 <= NT; tt += 2) {
      body(DB0{}, tt);
      body(DB1{}, tt + 1);
    }
    if (tt < NT) body(DB0{}, tt);
  }

#pragma unroll
  for (int n = 0; n < 4; n++) {
    int colg = n0 + wn * 64 + n * 16 + q;
    float bv = bias ? bias[colg] : 0.f;
#pragma unroll
    for (int m = 0; m < 4; m++) {
      int rowb = m0 + wm * 64 + m * 16 + g * 4;
#pragma unroll
      for (int r = 0; r < 4; r++) {
        float val = acc[m][n][r] * scale + bv;
        if (maskC && colg > rowb + r) val = -1e30f;
        if (OUTBF) {
          ((unsigned short*)Cv)[(size_t)(rowb + r) * ldc + colg] = f2bf(val);
        } else {
          ((float*)Cv)[(size_t)(rowb + r) * ldc + colg] = val;
        }
      }
    }
  }
}

// ======== r10 GEMM body: 128x128, BK=32, depth-3 ring (SV kernel) ========
__device__ __forceinline__ void gemm_body32(
    unsigned short (*lds)[8192],
    const unsigned short* __restrict__ A, int lda,
    const unsigned short* __restrict__ Bt, int ldb,
    unsigned short* __restrict__ C, int ldc,
    int NT, float scale, bool maskC, int m0, int n0) {
  const int t = threadIdx.x;
  const int lane = t & 63, wid = t >> 6;
  const int g = lane >> 4, q = lane & 15;
  const int wm = wid >> 1, wn = wid & 1;

  f32x4 acc[4][4] = {};

  {
    const int scol = ((t & 3) ^ ((t >> 3) & 3)) * 8;
    const unsigned short* aS = A + (size_t)(m0 + (t >> 2)) * lda + scol;
    const unsigned short* bS = Bt + (size_t)(n0 + (t >> 2)) * ldb + scol;

    auto stage = [&](int tt, int buf) {
      unsigned short* d = &lds[buf][wid * 512];
      const unsigned short* sa = aS + (size_t)tt * 32;
      const unsigned short* sb = bS + (size_t)tt * 32;
      gload16(sa, d);
      gload16(sa + (size_t)64 * lda, d + 2048);
      gload16(sb, d + 4096);
      gload16(sb + (size_t)64 * ldb, d + 6144);
    };

    const unsigned base =
        (unsigned)(unsigned long long)(__attribute__((address_space(3))) unsigned short*)&lds[0][0];
    const int cb = ((g ^ ((q >> 1) & 3)) << 4);
    const unsigned aaB = base + (unsigned)((wm * 64 + q) * 64 + cb);
    const unsigned bbB = base + 8192u + (unsigned)((wn * 64 + q) * 64 + cb);

    stage(0, 0);

    auto body = [&](auto dbc, int tt) {
      constexpr int DB = decltype(dbc)::value;
      if (tt + 1 < NT) {
        stage(tt + 1, (DB + 1) % 3);
        asm volatile("s_waitcnt vmcnt(4)" ::: "memory");
      } else {
        asm volatile("s_waitcnt vmcnt(0)" ::: "memory");
      }
      bar();
      const unsigned aa = aaB + DB * 16384u;
      const unsigned bb = bbB + DB * 16384u;
      short8 aq[4], bq[4];
      aq[0] = dsr<0>(aa);
      aq[1] = dsr<1024>(aa);
      aq[2] = dsr<2048>(aa);
      aq[3] = dsr<3072>(aa);
      bq[0] = dsr<0>(bb);
      bq[1] = dsr<1024>(bb);
      bq[2] = dsr<2048>(bb);
      bq[3] = dsr<3072>(bb);
      asm volatile("s_waitcnt lgkmcnt(0)" ::: "memory");
      __builtin_amdgcn_sched_barrier(0);
      __builtin_amdgcn_s_setprio(1);
#pragma unroll
      for (int m = 0; m < 4; m++)
#pragma unroll
        for (int n = 0; n < 4; n++)
          acc[m][n] = __builtin_amdgcn_mfma_f32_16x16x32_bf16(aq[m], bq[n], acc[m][n], 0, 0, 0);
      __builtin_amdgcn_s_setprio(0);
      __builtin_amdgcn_sched_barrier(0);
    };

    int tt = 0;
    for (; tt + 3 <= NT; tt += 3) {
      body(DB0{}, tt);
      body(DB1{}, tt + 1);
      body(DB2{}, tt + 2);
    }
    if (tt < NT) body(DB0{}, tt);
    if (tt + 1 < NT) body(DB1{}, tt + 1);
  }

#pragma unroll
  for (int n = 0; n < 4; n++) {
    int colg = n0 + wn * 64 + n * 16 + q;
#pragma unroll
    for (int m = 0; m < 4; m++) {
      int rowb = m0 + wm * 64 + m * 16 + g * 4;
#pragma unroll
      for (int r = 0; r < 4; r++) {
        float val = acc[m][n][r] * scale;
        if (maskC && colg > rowb + r) val = -1e30f;
        C[(size_t)(rowb + r) * ldc + colg] = f2bf(val);
      }
    }
  }
}

// ---- GEMM1 wrapper (r6 body) ----
template <int OUTBF>
__global__ __launch_bounds__(256) void gemm128_kernel(
    const unsigned short* __restrict__ A, int lda, long long saz,
    const unsigned short* __restrict__ Bt, int ldb, long long sbz,
    void* __restrict__ Cv, int ldc, long long scz,
    const float* __restrict__ bias, int K, float scale, int causal) {
  __shared__ __align__(16) unsigned short lds[2][16384];
  int bx = blockIdx.x, by = blockIdx.y, z = blockIdx.z;
  const int m0 = by * 128, n0 = bx * 128;
  int NT = K >> 6;
  char* C = (char*)Cv + (size_t)z * scz * (OUTBF ? 2 : 4);
  gemm_body<OUTBF>(lds, A + (size_t)z * saz, lda, Bt + (size_t)z * sbz, ldb,
                   C, ldc, bias, NT, scale, false, m0, n0);
}

// ---- fused S + V' launch (r16, best measured): flat 1056 blocks ----
__global__ __launch_bounds__(256, 3) void gemm_sv_kernel(
    const unsigned short* __restrict__ qkv,
    const unsigned short* __restrict__ wtp,
    unsigned short* __restrict__ S,
    unsigned short* __restrict__ vt) {
  __shared__ __align__(16) unsigned short lds[3][8192];
  int i = blockIdx.x;
  if (i < 512) {
    int bx = i & 15, by = (i >> 4) & 7, z = i >> 7;
    gemm_body32(lds, wtp, 1024,
                qkv + 2048 + (size_t)z * 2048 * 3072, 3072,
                vt + (size_t)z * 1024 * 2048, 2048,
                32, 1.0f, false, by * 128, bx * 128);
  } else {
    int ii = i - 512;
    int z = ii / 136, tri = ii % 136;
    int by = (int)((sqrtf(8.f * tri + 1.f) - 1.f) * 0.5f);
    while ((by + 1) * (by + 2) / 2 <= tri) by++;
    while (by * (by + 1) / 2 > tri) by--;
    int bx = tri - by * (by + 1) / 2;
    gemm_body32(lds, qkv + (size_t)z * 2048 * 3072, 3072,
                qkv + 1024 + (size_t)z * 2048 * 3072, 3072,
                S + (size_t)z * 2048 * 2048, 2048,
                32, 0.125f, true, by * 128, bx * 128);
  }
}

// ==== PV with FUSED softmax: out = softmax_row(S_raw) @ V' + bias =========
// Prepass: 2 threads/row online max/sum over raw S cols [0, m0+128).
// Main loop: r6 drain schedule; A (P) is reg-staged: load raw S short8,
// p = exp2((v - mx_row)*log2e), ds_write to the standard LDS layout.
// 1/sum applied in f32 epilogue. Grid (8,16,4) with balanced by-remap.
__global__ __launch_bounds__(256) void pv_kernel(
    const unsigned short* __restrict__ S,
    const unsigned short* __restrict__ vt,
    float* __restrict__ out,
    const float* __restrict__ bp) {
  __shared__ __align__(16) unsigned short lds[2][16384];
  __shared__ float pm[2][128], ps[2][128];
  __shared__ float mrow[128], isum[128];

  // balanced remap: pair (by0, 15-by0) across co-resident halves
  int bx, by, z;
  {
    int gx = gridDim.x, gy = gridDim.y, gz = gridDim.z;
    int total = gx * gy * gz;
    int id = blockIdx.x + blockIdx.y * gx + blockIdx.z * gx * gy;
    int halfn = total >> 1;
    int half = id >= halfn;
    int r = id - half * halfn;
    bx = r % gx;
    int rest = r / gx;
    int by0 = rest % gy;
    z = rest / gy + half * (gz >> 1);
    by = half ? (gy - 1 - by0) : by0;
  }
  const int m0 = by * 128, n0 = bx * 128;
  const int rend = m0 + 128;
  const int NT = rend >> 6;
  const unsigned short* Sz = S + (size_t)z * 2048 * 2048;
  const unsigned short* Vz = vt + (size_t)z * 1024 * 2048;

  const int t = threadIdx.x;
  const int lane = t & 63, wid = t >> 6;
  const int g = lane >> 4, q = lane & 15;
  const int wm = wid >> 1, wn = wid & 1;
  const float L2E = 1.44269504f;

  // ---- prepass: online row max/sum ----
  {
    int r = t & 127, half = t >> 7;
    int rend2 = rend >> 1;
    const unsigned short* p = Sz + (size_t)(m0 + r) * 2048 + half * rend2;
    float m = -3e38f, s = 0.f;
    for (int c = 0; c < rend2; c += 8) {
      short8 raw = *(const short8*)&p[c];
      float v[8];
#pragma unroll
      for (int j = 0; j < 8; j++) v[j] = bf2f((unsigned short)raw[j]);
      float bm = v[0];
#pragma unroll
      for (int j = 1; j < 8; j++) bm = fmaxf(bm, v[j]);
      if (bm > m) { s *= exp2f((m - bm) * L2E); m = bm; }
#pragma unroll
      for (int j = 0; j < 8; j++) s += exp2f((v[j] - m) * L2E);
    }
    pm[half][r] = m; ps[half][r] = s;
  }
  __syncthreads();
  if (t < 128) {
    float ma = pm[0][t], mb = pm[1][t];
    float mm = fmaxf(ma, mb);
    float ss = ps[0][t] * exp2f((ma - mm) * L2E) + ps[1][t] * exp2f((mb - mm) * L2E);
    mrow[t] = mm; isum[t] = 1.f / ss;
  }
  __syncthreads();

  f32x4 acc[4][4] = {};

  {
    const int scol = ((t & 7) * 8) ^ ((t & 32) >> 1);
    const unsigned short* aS = Sz + (size_t)(m0 + (t >> 3)) * 2048 + scol;
    const unsigned short* bS = Vz + (size_t)(n0 + (t >> 3)) * 2048 + scol;

    // per-thread row maxima for the 4 A-subrows (fixed across tiles)
    float mr[4];
#pragma unroll
    for (int i = 0; i < 4; i++) mr[i] = mrow[(t >> 3) + i * 32];

    auto stageB = [&](int tt) {
      unsigned short* d = &lds[tt & 1][wid * 512];
      const unsigned short* sb = bS + (size_t)tt * 64;
      gload16(sb, d + 8192);
      gload16(sb + (size_t)32 * 2048, d + 10240);
      gload16(sb + (size_t)64 * 2048, d + 12288);
      gload16(sb + (size_t)96 * 2048, d + 14336);
    };
    auto loadA = [&](int tt, short8* ar) {
#pragma unroll
      for (int i = 0; i < 4; i++)
        ar[i] = *(const short8*)(aS + (size_t)i * 32 * 2048 + (size_t)tt * 64);
    };
    auto writeA = [&](int tt, short8* ar) {
      unsigned short* d = &lds[tt & 1][wid * 512 + (lane & 63) * 8];
#pragma unroll
      for (int i = 0; i < 4; i++) {
        short8 o;
#pragma unroll
        for (int j = 0; j < 8; j++) {
          float v = bf2f((unsigned short)ar[i][j]);
          o[j] = (short)f2bf(exp2f((v - mr[i]) * L2E));
        }
        *(short8*)&d[i * 2048] = o;
      }
    };

    const unsigned base =
        (unsigned)(unsigned long long)(__attribute__((address_space(3))) unsigned short*)&lds[0][0];
    const int colA = (g * 16) ^ ((q & 4) << 3);
    const unsigned aaB = base + (unsigned)((wm * 64 + q) * 128 + colA);
    const unsigned bbB = base + 16384u + (unsigned)((wn * 64 + q) * 128 + colA);

    // prologue: tile 0
    {
      short8 a0[4];
      stageB(0);
      loadA(0, a0);
      asm volatile("s_waitcnt vmcnt(0)" ::: "memory");
      writeA(0, a0);
      asm volatile("s_waitcnt lgkmcnt(0)" ::: "memory");
      bar();
    }

    auto body = [&](auto dbc, int tt) {
      constexpr int DB = decltype(dbc)::value;
      const unsigned aa = aaB + DB * 32768u;
      const unsigned bb = bbB + DB * 32768u;
      short8 an[4];
      const bool more = (tt + 1 < NT);
      if (more) {
        stageB(tt + 1);
        loadA(tt + 1, an);
      }
      short8 aq[4][2], bq[4][2];
#pragma unroll
      for (int m = 0; m < 4; m++) {
        aq[m][0] = dsr<0>(aa + m * 2048u);
        aq[m][1] = dsr<64>(aa + m * 2048u);
      }
#pragma unroll
      for (int n = 0; n < 4; n++) {
        bq[n][0] = dsr<0>(bb + n * 2048u);
        bq[n][1] = dsr<64>(bb + n * 2048u);
      }
      asm volatile("s_waitcnt lgkmcnt(0)" ::: "memory");
      __builtin_amdgcn_sched_barrier(0);
      __builtin_amdgcn_s_setprio(1);
#pragma unroll
      for (int ks = 0; ks < 2; ks++)
#pragma unroll
        for (int m = 0; m < 4; m++)
#pragma unroll
          for (int n = 0; n < 4; n++)
            acc[m][n] = __builtin_amdgcn_mfma_f32_16x16x32_bf16(aq[m][ks], bq[n][ks], acc[m][n], 0, 0, 0);
      __builtin_amdgcn_s_setprio(0);
      __builtin_amdgcn_sched_barrier(0);
      asm volatile("s_waitcnt vmcnt(0)" ::: "memory");
      if (more) {
        writeA(tt + 1, an);
        asm volatile("s_waitcnt lgkmcnt(0)" ::: "memory");
      }
      bar();
    };

    int tt = 0;
    for (; tt + 2 <= NT; tt += 2) {
      body(DB0{}, tt);
      body(DB1{}, tt + 1);
    }
    if (tt < NT) body(DB0{}, tt);
  }

  // ---- epilogue: apply 1/sum (f32) + bias ----
  float* oz = out + (size_t)z * 2048 * 1024;
#pragma unroll
  for (int n = 0; n < 4; n++) {
    int colg = n0 + wn * 64 + n * 16 + q;
    float bv = bp[colg];
#pragma unroll
    for (int m = 0; m < 4; m++) {
      int rowl = wm * 64 + m * 16 + g * 4;
#pragma unroll
      for (int r = 0; r < 4; r++) {
        float val = acc[m][n][r] * isum[rowl + r] + bv;
        oz[(size_t)(m0 + rowl + r) * 1024 + colg] = val;
      }
    }
  }
}

extern "C" void kernel_launch(void* const* d_in, const int* in_sizes, int n_in,
                              void* d_out, int out_size, void* d_ws, size_t ws_size,
                              hipStream_t stream) {
  const float* x  = (const float*)d_in[0];
  const float* Wa = (const float*)d_in[1];
  const float* ba = (const float*)d_in[2];
  const float* Wp = (const float*)d_in[3];
  const float* bp = (const float*)d_in[4];
  float* out = (float*)d_out;

  char* ws = (char*)d_ws;
  unsigned short* qkv = (unsigned short*)(ws);                 // 50331648
  unsigned short* xb  = (unsigned short*)(ws + 50331648);      // 16777216
  unsigned short* vt  = (unsigned short*)(ws + 50331648);      // V'^T, overlays xb
  unsigned short* wta = (unsigned short*)(ws + 67108864);      // 6291456
  unsigned short* S   = (unsigned short*)(ws + 73400320);      // 33554432 (raw logits)
  unsigned short* wtp = (unsigned short*)(ws + 123731968);     // 2097152

  prep_kernel<<<12288, 256, 0, stream>>>(x, xb, Wa, wta, Wp, wtp);

  // qkv = x @ W_attn + b_attn   [8192 x 3072]
  gemm128_kernel<1><<<dim3(24, 64, 1), 256, 0, stream>>>(
      xb, 1024, 0, wta, 1024, 0, qkv, 3072, 0, ba, 1024, 1.0f, 0);

  // fused: V'^T (512 blocks) + causal S-raw triangle (544 blocks)
  gemm_sv_kernel<<<1056, 256, 0, stream>>>(qkv, wtp, S, vt);

  // out = softmax(S) @ V' + b_proj, softmax fused into PV
  pv_kernel<<<dim3(8, 16, 4), 256, 0, stream>>>(S, vt, out, bp);
}

// Round 18
// 184.480 us; speedup vs baseline: 1.3465x; 1.3465x over previous
//
#include <hip/hip_runtime.h>

typedef __attribute__((ext_vector_type(8))) short short8;
typedef __attribute__((ext_vector_type(4))) float f32x4;
typedef __attribute__((ext_vector_type(4))) unsigned short ushort4v;

struct DB0 { static constexpr int value = 0; };
struct DB1 { static constexpr int value = 1; };
struct DB2 { static constexpr int value = 2; };

__device__ __forceinline__ unsigned short f2bf(float f) {
  unsigned int u = __float_as_uint(f);
  u += 0x7fffu + ((u >> 16) & 1u);
  return (unsigned short)(u >> 16);
}
__device__ __forceinline__ float bf2f(unsigned short h) {
  return __uint_as_float(((unsigned int)h) << 16);
}

__device__ __forceinline__ void gload16(const unsigned short* g, unsigned short* l) {
  __builtin_amdgcn_global_load_lds(
      (const __attribute__((address_space(1))) unsigned int*)g,
      (__attribute__((address_space(3))) unsigned int*)l,
      16, 0, 0);
}

template <int OFF>
__device__ __forceinline__ short8 dsr(unsigned a) {
  short8 r;
  asm volatile("ds_read_b128 %0, %1 offset:%2" : "=v"(r) : "v"(a), "n"(OFF));
  return r;
}

__device__ __forceinline__ void bar() {
  asm volatile("" ::: "memory");
  __builtin_amdgcn_s_barrier();
  asm volatile("" ::: "memory");
}

// ---- merged prep: conv x->bf16 (8192 blks) | W_attn^T (3072) | W_proj^T (1024)
__global__ __launch_bounds__(256) void prep_kernel(
    const float* __restrict__ x, unsigned short* __restrict__ xb,
    const float* __restrict__ Wa, unsigned short* __restrict__ wta,
    const float* __restrict__ Wp, unsigned short* __restrict__ wtp) {
  int b = blockIdx.x;
  int tx = threadIdx.x & 31, ty = threadIdx.x >> 5;
  if (b < 8192) {
    int i = b * 256 + threadIdx.x;
    f32x4 v = ((const f32x4*)x)[i];
    ushort4v o;
    o[0] = f2bf(v[0]); o[1] = f2bf(v[1]); o[2] = f2bf(v[2]); o[3] = f2bf(v[3]);
    ((ushort4v*)xb)[i] = o;
    return;
  }
  const float* W; unsigned short* Wt; int K, N, n0, k0;
  if (b < 8192 + 3072) {
    int bb = b - 8192; W = Wa; Wt = wta; K = 1024; N = 3072;
    n0 = (bb % 96) * 32; k0 = (bb / 96) * 32;
  } else {
    int bb = b - 11264; W = Wp; Wt = wtp; K = 1024; N = 1024;
    n0 = (bb % 32) * 32; k0 = (bb / 32) * 32;
  }
  __shared__ float tile[32][33];
#pragma unroll
  for (int j = 0; j < 32; j += 8)
    tile[ty + j][tx] = W[(size_t)(k0 + ty + j) * N + n0 + tx];
  __syncthreads();
#pragma unroll
  for (int j = 0; j < 32; j += 8)
    Wt[(size_t)(n0 + ty + j) * K + k0 + tx] = f2bf(tile[tx][ty + j]);
}

// ------- row softmax on S (bf16, in place), causal-variable length -------
__global__ __launch_bounds__(256) void softmax_kernel(unsigned short* __restrict__ S) {
  int row = blockIdx.x * 4 + (threadIdx.x >> 6);
  int l = threadIdx.x & 63;
  int rl = row & 2047;
  int rend = ((rl >> 7) + 1) << 7;
  unsigned short* p = S + (size_t)row * 2048;
  float v[32];
  float mx = -3e38f;
#pragma unroll
  for (int i = 0; i < 4; i++) {
    int c0 = (i * 64 + l) * 8;
    if (c0 < rend) {
      short8 raw = *(const short8*)&p[c0];
#pragma unroll
      for (int j = 0; j < 8; j++) {
        v[i * 8 + j] = bf2f((unsigned short)raw[j]);
        mx = fmaxf(mx, v[i * 8 + j]);
      }
    } else {
#pragma unroll
      for (int j = 0; j < 8; j++) v[i * 8 + j] = -3e38f;
    }
  }
#pragma unroll
  for (int off = 1; off < 64; off <<= 1) mx = fmaxf(mx, __shfl_xor(mx, off));
  float s = 0.f;
#pragma unroll
  for (int i = 0; i < 32; i++) { v[i] = exp2f((v[i] - mx) * 1.44269504f); s += v[i]; }
#pragma unroll
  for (int off = 1; off < 64; off <<= 1) s += __shfl_xor(s, off);
  float inv = 1.f / s;
#pragma unroll
  for (int i = 0; i < 4; i++) {
    int c0 = (i * 64 + l) * 8;
    if (c0 < rend) {
      short8 o;
#pragma unroll
      for (int j = 0; j < 8; j++) o[j] = (short)f2bf(v[i * 8 + j] * inv);
      *(short8*)&p[c0] = o;
    }
  }
}

// ======== r6 GEMM body: 128x128, BK=64, depth-2, drain schedule ========
template <int OUTBF>
__device__ __forceinline__ void gemm_body(
    unsigned short (*lds)[16384],
    const unsigned short* __restrict__ A, int lda,
    const unsigned short* __restrict__ Bt, int ldb,
    void* __restrict__ Cv, int ldc,
    const float* __restrict__ bias, int NT, float scale, bool maskC,
    int m0, int n0) {
  const int t = threadIdx.x;
  const int lane = t & 63, wid = t >> 6;
  const int g = lane >> 4, q = lane & 15;
  const int wm = wid >> 1, wn = wid & 1;

  f32x4 acc[4][4] = {};

  {
    const int scol = ((t & 7) * 8) ^ ((t & 32) >> 1);
    const unsigned short* aS = A + (size_t)(m0 + (t >> 3)) * lda + scol;
    const unsigned short* bS = Bt + (size_t)(n0 + (t >> 3)) * ldb + scol;

    auto stage = [&](int tt) {
      unsigned short* d = &lds[tt & 1][wid * 512];
      const unsigned short* sa = aS + (size_t)tt * 64;
      const unsigned short* sb = bS + (size_t)tt * 64;
      gload16(sa, d);
      gload16(sa + (size_t)32 * lda, d + 2048);
      gload16(sa + (size_t)64 * lda, d + 4096);
      gload16(sa + (size_t)96 * lda, d + 6144);
      gload16(sb, d + 8192);
      gload16(sb + (size_t)32 * ldb, d + 10240);
      gload16(sb + (size_t)64 * ldb, d + 12288);
      gload16(sb + (size_t)96 * ldb, d + 14336);
    };

    const unsigned base =
        (unsigned)(unsigned long long)(__attribute__((address_space(3))) unsigned short*)&lds[0][0];
    const int colA = (g * 16) ^ ((q & 4) << 3);
    const unsigned aaB = base + (unsigned)((wm * 64 + q) * 128 + colA);
    const unsigned bbB = base + 16384u + (unsigned)((wn * 64 + q) * 128 + colA);

    stage(0);
    asm volatile("s_waitcnt vmcnt(0)" ::: "memory");
    bar();

    auto body = [&](auto dbc, int tt) {
      constexpr int DB = decltype(dbc)::value;
      const unsigned aa = aaB + DB * 32768u;
      const unsigned bb = bbB + DB * 32768u;
      if (tt + 1 < NT) stage(tt + 1);
      short8 aq[4][2], bq[4][2];
#pragma unroll
      for (int m = 0; m < 4; m++) {
        aq[m][0] = dsr<0>(aa + m * 2048u);
        aq[m][1] = dsr<64>(aa + m * 2048u);
      }
#pragma unroll
      for (int n = 0; n < 4; n++) {
        bq[n][0] = dsr<0>(bb + n * 2048u);
        bq[n][1] = dsr<64>(bb + n * 2048u);
      }
      asm volatile("s_waitcnt lgkmcnt(0)" ::: "memory");
      __builtin_amdgcn_sched_barrier(0);
      __builtin_amdgcn_s_setprio(1);
#pragma unroll
      for (int ks = 0; ks < 2; ks++)
#pragma unroll
        for (int m = 0; m < 4; m++)
#pragma unroll
          for (int n = 0; n < 4; n++)
            acc[m][n] = __builtin_amdgcn_mfma_f32_16x16x32_bf16(aq[m][ks], bq[n][ks], acc[m][n], 0, 0, 0);
      __builtin_amdgcn_s_setprio(0);
      __builtin_amdgcn_sched_barrier(0);
      asm volatile("s_waitcnt vmcnt(0)" ::: "memory");
      bar();
    };

    int tt = 0;
    for (; tt + 2 <= NT; tt += 2) {
      body(DB0{}, tt);
      body(DB1{}, tt + 1);
    }
    if (tt < NT) body(DB0{}, tt);
  }

#pragma unroll
  for (int n = 0; n < 4; n++) {
    int colg = n0 + wn * 64 + n * 16 + q;
    float bv = bias ? bias[colg] : 0.f;
#pragma unroll
    for (int m = 0; m < 4; m++) {
      int rowb = m0 + wm * 64 + m * 16 + g * 4;
#pragma unroll
      for (int r = 0; r < 4; r++) {
        float val = acc[m][n][r] * scale + bv;
        if (maskC && colg > rowb + r) val = -1e30f;
        if (OUTBF) {
          ((unsigned short*)Cv)[(size_t)(rowb + r) * ldc + colg] = f2bf(val);
        } else {
          ((float*)Cv)[(size_t)(rowb + r) * ldc + colg] = val;
        }
      }
    }
  }
}

// ======== r10 GEMM body: 128x128, BK=32, depth-3 ring (SV kernel) ========
__device__ __forceinline__ void gemm_body32(
    unsigned short (*lds)[8192],
    const unsigned short* __restrict__ A, int lda,
    const unsigned short* __restrict__ Bt, int ldb,
    unsigned short* __restrict__ C, int ldc,
    int NT, float scale, bool maskC, int m0, int n0) {
  const int t = threadIdx.x;
  const int lane = t & 63, wid = t >> 6;
  const int g = lane >> 4, q = lane & 15;
  const int wm = wid >> 1, wn = wid & 1;

  f32x4 acc[4][4] = {};

  {
    const int scol = ((t & 3) ^ ((t >> 3) & 3)) * 8;
    const unsigned short* aS = A + (size_t)(m0 + (t >> 2)) * lda + scol;
    const unsigned short* bS = Bt + (size_t)(n0 + (t >> 2)) * ldb + scol;

    auto stage = [&](int tt, int buf) {
      unsigned short* d = &lds[buf][wid * 512];
      const unsigned short* sa = aS + (size_t)tt * 32;
      const unsigned short* sb = bS + (size_t)tt * 32;
      gload16(sa, d);
      gload16(sa + (size_t)64 * lda, d + 2048);
      gload16(sb, d + 4096);
      gload16(sb + (size_t)64 * ldb, d + 6144);
    };

    const unsigned base =
        (unsigned)(unsigned long long)(__attribute__((address_space(3))) unsigned short*)&lds[0][0];
    const int cb = ((g ^ ((q >> 1) & 3)) << 4);
    const unsigned aaB = base + (unsigned)((wm * 64 + q) * 64 + cb);
    const unsigned bbB = base + 8192u + (unsigned)((wn * 64 + q) * 64 + cb);

    stage(0, 0);

    auto body = [&](auto dbc, int tt) {
      constexpr int DB = decltype(dbc)::value;
      if (tt + 1 < NT) {
        stage(tt + 1, (DB + 1) % 3);
        asm volatile("s_waitcnt vmcnt(4)" ::: "memory");
      } else {
        asm volatile("s_waitcnt vmcnt(0)" ::: "memory");
      }
      bar();
      const unsigned aa = aaB + DB * 16384u;
      const unsigned bb = bbB + DB * 16384u;
      short8 aq[4], bq[4];
      aq[0] = dsr<0>(aa);
      aq[1] = dsr<1024>(aa);
      aq[2] = dsr<2048>(aa);
      aq[3] = dsr<3072>(aa);
      bq[0] = dsr<0>(bb);
      bq[1] = dsr<1024>(bb);
      bq[2] = dsr<2048>(bb);
      bq[3] = dsr<3072>(bb);
      asm volatile("s_waitcnt lgkmcnt(0)" ::: "memory");
      __builtin_amdgcn_sched_barrier(0);
      __builtin_amdgcn_s_setprio(1);
#pragma unroll
      for (int m = 0; m < 4; m++)
#pragma unroll
        for (int n = 0; n < 4; n++)
          acc[m][n] = __builtin_amdgcn_mfma_f32_16x16x32_bf16(aq[m], bq[n], acc[m][n], 0, 0, 0);
      __builtin_amdgcn_s_setprio(0);
      __builtin_amdgcn_sched_barrier(0);
    };

    int tt = 0;
    for (; tt + 3 <= NT; tt += 3) {
      body(DB0{}, tt);
      body(DB1{}, tt + 1);
      body(DB2{}, tt + 2);
    }
    if (tt < NT) body(DB0{}, tt);
    if (tt + 1 < NT) body(DB1{}, tt + 1);
  }

#pragma unroll
  for (int n = 0; n < 4; n++) {
    int colg = n0 + wn * 64 + n * 16 + q;
#pragma unroll
    for (int m = 0; m < 4; m++) {
      int rowb = m0 + wm * 64 + m * 16 + g * 4;
#pragma unroll
      for (int r = 0; r < 4; r++) {
        float val = acc[m][n][r] * scale;
        if (maskC && colg > rowb + r) val = -1e30f;
        C[(size_t)(rowb + r) * ldc + colg] = f2bf(val);
      }
    }
  }
}

// ---- GEMM1 and PV wrappers (r6 body) ----
template <int OUTBF>
__global__ __launch_bounds__(256) void gemm128_kernel(
    const unsigned short* __restrict__ A, int lda, long long saz,
    const unsigned short* __restrict__ Bt, int ldb, long long sbz,
    void* __restrict__ Cv, int ldc, long long scz,
    const float* __restrict__ bias, int K, float scale, int causal) {
  __shared__ __align__(16) unsigned short lds[2][16384];
  int bx, by, z;
  if (causal == 4) {
    int gx = gridDim.x, gy = gridDim.y, gz = gridDim.z;
    int total = gx * gy * gz;
    int id = blockIdx.x + blockIdx.y * gx + blockIdx.z * gx * gy;
    int halfn = total >> 1;
    int half = id >= halfn;
    int r = id - half * halfn;
    bx = r % gx;
    int rest = r / gx;
    int by0 = rest % gy;
    z = rest / gy + half * (gz >> 1);
    by = half ? (gy - 1 - by0) : by0;
  } else {
    bx = blockIdx.x; by = blockIdx.y; z = blockIdx.z;
  }
  const int m0 = by * 128, n0 = bx * 128;
  int NT = K >> 6;
  if (causal == 4) NT = min(K, m0 + 128) >> 6;
  char* C = (char*)Cv + (size_t)z * scz * (OUTBF ? 2 : 4);
  gemm_body<OUTBF>(lds, A + (size_t)z * saz, lda, Bt + (size_t)z * sbz, ldb,
                   C, ldc, bias, NT, scale, false, m0, n0);
}

// ---- fused S + V' launch: flat 1056 blocks, r10 body (3 blk/CU) ----
// ids [0,512):   V'^T = Wp^T @ V^T  (bx=i&15, by=(i>>4)&7, z=i>>7)
// ids [512,1056): S = Q K^T * 0.125 causal, triangular (136/batch)
__global__ __launch_bounds__(256, 3) void gemm_sv_kernel(
    const unsigned short* __restrict__ qkv,
    const unsigned short* __restrict__ wtp,
    unsigned short* __restrict__ S,
    unsigned short* __restrict__ vt) {
  __shared__ __align__(16) unsigned short lds[3][8192];
  int i = blockIdx.x;
  if (i < 512) {
    int bx = i & 15, by = (i >> 4) & 7, z = i >> 7;
    gemm_body32(lds, wtp, 1024,
                qkv + 2048 + (size_t)z * 2048 * 3072, 3072,
                vt + (size_t)z * 1024 * 2048, 2048,
                32, 1.0f, false, by * 128, bx * 128);
  } else {
    int ii = i - 512;
    int z = ii / 136, tri = ii % 136;
    int by = (int)((sqrtf(8.f * tri + 1.f) - 1.f) * 0.5f);
    while ((by + 1) * (by + 2) / 2 <= tri) by++;
    while (by * (by + 1) / 2 > tri) by--;
    int bx = tri - by * (by + 1) / 2;
    gemm_body32(lds, qkv + (size_t)z * 2048 * 3072, 3072,
                qkv + 1024 + (size_t)z * 2048 * 3072, 3072,
                S + (size_t)z * 2048 * 2048, 2048,
                32, 0.125f, true, by * 128, bx * 128);
  }
}

extern "C" void kernel_launch(void* const* d_in, const int* in_sizes, int n_in,
                              void* d_out, int out_size, void* d_ws, size_t ws_size,
                              hipStream_t stream) {
  const float* x  = (const float*)d_in[0];
  const float* Wa = (const float*)d_in[1];
  const float* ba = (const float*)d_in[2];
  const float* Wp = (const float*)d_in[3];
  const float* bp = (const float*)d_in[4];
  float* out = (float*)d_out;

  char* ws = (char*)d_ws;
  unsigned short* qkv = (unsigned short*)(ws);                 // 50331648
  unsigned short* xb  = (unsigned short*)(ws + 50331648);      // 16777216
  unsigned short* vt  = (unsigned short*)(ws + 50331648);      // V'^T, overlays xb
  unsigned short* wta = (unsigned short*)(ws + 67108864);      // 6291456
  unsigned short* S   = (unsigned short*)(ws + 73400320);      // 33554432
  unsigned short* wtp = (unsigned short*)(ws + 123731968);     // 2097152

  prep_kernel<<<12288, 256, 0, stream>>>(x, xb, Wa, wta, Wp, wtp);

  // qkv = x @ W_attn + b_attn   [8192 x 3072]
  gemm128_kernel<1><<<dim3(24, 64, 1), 256, 0, stream>>>(
      xb, 1024, 0, wta, 1024, 0, qkv, 3072, 0, ba, 1024, 1.0f, 0);

  // fused: V'^T (512 blocks) + causal S triangle (544 blocks), 3 blk/CU
  gemm_sv_kernel<<<1056, 256, 0, stream>>>(qkv, wtp, S, vt);

  softmax_kernel<<<2048, 256, 0, stream>>>(S);

  // out = P @ V' + b_proj : [2048 x 1024] per batch, fp32, K-trunc balanced
  gemm128_kernel<0><<<dim3(8, 16, 4), 256, 0, stream>>>(
      S, 2048, 2048LL * 2048, vt, 2048, 2048LL * 1024,
      out, 1024, 2048LL * 1024, bp, 2048, 1.0f, 4);
}